// Round 4
// baseline (862.148 us; speedup 1.0000x reference)
//
#include <hip/hip_runtime.h>
#include <hip/hip_cooperative_groups.h>
namespace cg = cooperative_groups;

#define DM 256
#define DI 512
#define NL 10

// ws offsets (floats)
#define WS_POOLED 0
#define WS_GATES  40960
#define WS_SX     122880
#define WS_SH     204800
#define WS_XI     286720   // reused as y2 after conv consumes it
#define WS_ZB     450560
#define WS_XC     614400
#define WS_DBL    778240

__device__ __forceinline__ float dot4(float4 a, float4 b) {
    return a.x*b.x + a.y*b.y + a.z*b.z + a.w*b.w;
}
__device__ __forceinline__ float silu(float x) {
    return x / (1.f + __expf(-x));
}

// ---------------- Kernel 1: spatial mean pool of x1..x4 -> pooled (4,40,256)
__global__ void pool_kernel(const float* __restrict__ x1, const float* __restrict__ x2,
                            const float* __restrict__ x3, const float* __restrict__ x4,
                            float* __restrict__ pooled)
{
    int wid  = (blockIdx.x * blockDim.x + threadIdx.x) >> 6;
    int lane = threadIdx.x & 63;
    if (wid >= 40960) return;
    int img = wid / 10240;
    int r   = wid % 10240;
    const float* src; int hw;
    if      (img == 0) { src = x1; hw = 3136; }
    else if (img == 1) { src = x2; hw = 784; }
    else if (img == 2) { src = x3; hw = 196; }
    else               { src = x4; hw = 49; }
    const float* row = src + (size_t)r * hw;
    float s = 0.f;
    if (hw == 49) {
        if (lane < 49) s = row[lane];
    } else {
        int n4 = hw >> 2;
        for (int j = lane; j < n4; j += 64) {
            float4 v = *(const float4*)(row + j*4);
            s += v.x + v.y + v.z + v.w;
        }
    }
    #pragma unroll
    for (int off = 32; off; off >>= 1) s += __shfl_down(s, off);
    if (lane == 0) pooled[img*10240 + r] = s / (float)hw;
}

// ---------------- Kernel 2: one cooperative kernel for the entire encoder chain
__global__ __launch_bounds__(512)
void enc_coop(const float* __restrict__ audio, const float* __restrict__ vis_w,
              const float* __restrict__ vis_b, const float* __restrict__ ln_g,
              const float* __restrict__ ln_b,  const float* __restrict__ in_w,
              const float* __restrict__ conv_w,const float* __restrict__ conv_b,
              const float* __restrict__ xp_w,  const float* __restrict__ dt_w,
              const float* __restrict__ dt_b,  const float* __restrict__ A_log,
              const float* __restrict__ Dp,    const float* __restrict__ out_w,
              const float* __restrict__ gate_w,const float* __restrict__ gate_b,
              float* __restrict__ ws)
{
    cg::grid_group grid = cg::this_grid();
    __shared__ float lds[4*NL*DM];      // 40 KB, reused per phase
    const int tid = threadIdx.x;
    const int bi  = blockIdx.x;
    const int g   = bi*512 + tid;

    float* pooled = ws + WS_POOLED;
    float* gates  = ws + WS_GATES;
    float* sxB  = ws + WS_SX;
    float* shB  = ws + WS_SH;
    float* xiB  = ws + WS_XI;
    float* zbB  = ws + WS_ZB;
    float* xcB  = ws + WS_XC;
    float* dblB = ws + WS_DBL;

    // ---- P0: build encoder inputs sx
    if (bi < 32) {
        const int e = bi >> 2, b = bi & 3;
        if (e < 4) {
            float* sx = sxB + (e*4+b)*NL*DM;
            for (int i = tid; i < NL*DM; i += 512) sx[i] = audio[b*NL*DM + i];
        } else {
            const int img = e - 4;
            for (int i = tid; i < NL*DM; i += 512)
                lds[i] = pooled[img*10240 + b*NL*DM + i];
            __syncthreads();
            const int c = tid & 255, lh = tid >> 8;
            const float* w = vis_w + img*65536 + c*256;
            const float bias = vis_b[img*256 + c];
            float acc[5];
            #pragma unroll
            for (int i = 0; i < 5; i++) acc[i] = bias;
            for (int k4 = 0; k4 < 64; k4++) {
                float4 wv = *(const float4*)(w + k4*4);
                #pragma unroll
                for (int i = 0; i < 5; i++)
                    acc[i] += dot4(wv, *(const float4*)(&lds[(lh*5+i)*DM + k4*4]));
            }
            float* sx = sxB + (e*4+b)*NL*DM;
            #pragma unroll
            for (int i = 0; i < 5; i++) sx[(lh*5+i)*DM + c] = acc[i];
        }
    }
    grid.sync();

    for (int layer = 0; layer < 3; layer++) {
        // ---- P1: LN (redundant per chunk-block) + xz GEMM. 128 blocks = (e, chunk16)
        {
            const int e = bi >> 4, chunk = bi & 15;
            const int el = e*3 + layer;
            const int wv = tid >> 6, lane = tid & 63;
            #pragma unroll
            for (int i = 0; i < 5; i++) {
                int rr = wv*5 + i;                 // 0..39 = (b,l)
                int b = rr / 10, l = rr % 10;
                float4 v = *(const float4*)(sxB + (e*4+b)*2560 + l*256 + lane*4);
                float s  = v.x+v.y+v.z+v.w;
                float ss = dot4(v, v);
                #pragma unroll
                for (int off = 32; off; off >>= 1) {
                    s  += __shfl_xor(s, off);
                    ss += __shfl_xor(ss, off);
                }
                float m  = s * (1.f/256.f);
                float rs = rsqrtf(ss*(1.f/256.f) - m*m + 1e-5f);
                float4 gv = *(const float4*)(ln_g + el*256 + lane*4);
                float4 bv = *(const float4*)(ln_b + el*256 + lane*4);
                float4 hv;
                hv.x = (v.x-m)*rs*gv.x + bv.x;
                hv.y = (v.y-m)*rs*gv.y + bv.y;
                hv.z = (v.z-m)*rs*gv.z + bv.z;
                hv.w = (v.w-m)*rs*gv.w + bv.w;
                *(float4*)(&lds[(b*10+l)*256 + lane*4]) = hv;
                if (chunk == 0)
                    *(float4*)(shB + (e*4+b)*2560 + l*256 + lane*4) = hv;
            }
            __syncthreads();
            const int col = chunk*64 + (tid & 63);        // 0..1023
            const int b = (tid >> 6) & 3, lh = tid >> 8;
            const float* w = in_w + (size_t)el*262144 + (size_t)col*256;
            float acc[5];
            #pragma unroll
            for (int i = 0; i < 5; i++) acc[i] = 0.f;
            for (int k4 = 0; k4 < 64; k4++) {
                float4 wv = *(const float4*)(w + k4*4);
                #pragma unroll
                for (int i = 0; i < 5; i++)
                    acc[i] += dot4(wv, *(const float4*)(&lds[(b*10+lh*5+i)*256 + k4*4]));
            }
            float* dst = (col < 512) ? xiB + (e*4+b)*5120 + col
                                     : zbB + (e*4+b)*5120 + (col - 512);
            #pragma unroll
            for (int i = 0; i < 5; i++) dst[(lh*5+i)*512] = acc[i];
        }
        grid.sync();

        // ---- P2: causal conv + silu. 16384 threads = (e,b,d)
        if (g < 16384) {
            const int e = g >> 11, b = (g >> 9) & 3, d = g & 511;
            const int el = e*3 + layer;
            const float* xi = xiB + (e*4+b)*5120;
            float* xc = xcB + (e*4+b)*5120;
            float4 cw = *(const float4*)(conv_w + el*2048 + d*4);
            float cb = conv_b[el*512 + d];
            float x0 = 0.f, x1 = 0.f, x2 = 0.f;
            #pragma unroll
            for (int l = 0; l < NL; l++) {
                float x3 = xi[l*512 + d];
                float a = cb + x3*cw.w + x2*cw.z + x1*cw.y + x0*cw.x;
                xc[l*512 + d] = silu(a);
                x0 = x1; x1 = x2; x2 = x3;
            }
        }
        grid.sync();

        // ---- P3: dbl GEMM. 30720 threads = 2 per (e,b,l,r) dot
        if (g < 30720) {
            const int half = g & 1;
            const int dt = g >> 1;                 // 0..15359
            const int r  = dt % 48;
            const int l  = (dt / 48) % 10;
            const int eb = dt / 480;               // 0..31
            const int e  = eb >> 2;
            const int el = e*3 + layer;
            const float* w  = xp_w + el*24576 + r*512 + half*256;
            const float* xc = xcB + eb*5120 + l*512 + half*256;
            float acc = 0.f;
            for (int k4 = 0; k4 < 64; k4++)
                acc += dot4(*(const float4*)(w + k4*4), *(const float4*)(xc + k4*4));
            acc += __shfl_xor(acc, 1);
            if (!half) dblB[eb*480 + l*48 + r] = acc;
        }
        grid.sync();

        // ---- P4: delta -> softplus -> scan -> y2 (*silu(z)). blocks 0..31 = (e,b)
        if (bi < 32) {
            if (tid < 480) lds[tid] = dblB[bi*480 + tid];
            __syncthreads();
            const int e = bi >> 2;
            const int el = e*3 + layer;
            const int d = tid;
            const float* dwp = dt_w + el*8192 + d*16;
            float4 dw0 = *(const float4*)(dwp);
            float4 dw1 = *(const float4*)(dwp + 4);
            float4 dw2 = *(const float4*)(dwp + 8);
            float4 dw3 = *(const float4*)(dwp + 12);
            float dbv = dt_b[el*512 + d];
            float Dpv = Dp[el*512 + d];
            float Av[16];
            #pragma unroll
            for (int n = 0; n < 16; n++) Av[n] = -__expf(A_log[el*8192 + d*16 + n]);
            const float* xc = xcB + bi*5120;
            const float* zb = zbB + bi*5120;
            float* y2 = xiB + bi*5120;
            float h[16];
            #pragma unroll
            for (int n = 0; n < 16; n++) h[n] = 0.f;
            #pragma unroll
            for (int l = 0; l < NL; l++) {
                float4 t0 = *(const float4*)(&lds[l*48]);
                float4 t1 = *(const float4*)(&lds[l*48 + 4]);
                float4 t2 = *(const float4*)(&lds[l*48 + 8]);
                float4 t3 = *(const float4*)(&lds[l*48 + 12]);
                float a = dbv + dot4(t0,dw0) + dot4(t1,dw1) + dot4(t2,dw2) + dot4(t3,dw3);
                float dl = fmaxf(a, 0.f) + log1pf(__expf(-fabsf(a)));
                float xcv = xc[l*512 + d];
                float du = dl * xcv;
                float y = 0.f;
                #pragma unroll
                for (int n = 0; n < 16; n++) {
                    float Bn = lds[l*48 + 16 + n];
                    float Cn = lds[l*48 + 32 + n];
                    h[n] = __expf(dl*Av[n])*h[n] + du*Bn;
                    y += h[n]*Cn;
                }
                y2[l*512 + d] = (y + xcv*Dpv) * silu(zb[l*512 + d]);
            }
        }
        grid.sync();

        // ---- P5: out GEMM + residual (sx = sh + y2 @ out_w.T). 2 thr per (e,b,o)
        if (g < 16384) {
            const int half = g & 1;
            const int dt = g >> 1;                  // 0..8191
            const int o = dt & 255, b = (dt >> 8) & 3, e = dt >> 10;
            const int el = e*3 + layer;
            const float* w  = out_w + (size_t)el*131072 + (size_t)o*512 + half*256;
            const float* y2 = xiB + (e*4+b)*5120 + half*256;
            float acc[NL];
            #pragma unroll
            for (int l = 0; l < NL; l++) acc[l] = 0.f;
            for (int k4 = 0; k4 < 64; k4++) {
                float4 wv = *(const float4*)(w + k4*4);
                #pragma unroll
                for (int l = 0; l < NL; l++)
                    acc[l] += dot4(wv, *(const float4*)(y2 + l*512 + k4*4));
            }
            #pragma unroll
            for (int l = 0; l < NL; l++) {
                acc[l] += __shfl_xor(acc[l], 1);
                if (!half) {
                    int idx = (e*4+b)*2560 + l*256 + o;
                    sxB[idx] = shB[idx] + acc[l];
                }
            }
        }
        grid.sync();
    }

    // ---- P6: gate GEMM + silu. 8192 threads = (e,b,o)
    if (g < 8192) {
        const int o = g & 255, b = (g >> 8) & 3, e = g >> 10;
        const float* sx = sxB + (e*4+b)*2560;
        const float* w = gate_w + e*65536 + o*256;
        float gb = gate_b[e*256 + o];
        float acc[NL];
        #pragma unroll
        for (int l = 0; l < NL; l++) acc[l] = gb;
        for (int k4 = 0; k4 < 64; k4++) {
            float4 wv = *(const float4*)(w + k4*4);
            #pragma unroll
            for (int l = 0; l < NL; l++)
                acc[l] += dot4(wv, *(const float4*)(sx + l*256 + k4*4));
        }
        #pragma unroll
        for (int l = 0; l < NL; l++)
            gates[(e*40 + b*10 + l)*256 + o] = silu(acc[l]);
    }
}

// ---------------- Kernel 3: x_out = x*(1+gate), plus ao tail blocks
__global__ void scale_ao_kernel(const float* __restrict__ x1, const float* __restrict__ x2,
                                const float* __restrict__ x3, const float* __restrict__ x4,
                                const float* __restrict__ audio,
                                const float* __restrict__ gates, float* __restrict__ out)
{
    int wid  = (blockIdx.x * blockDim.x + threadIdx.x) >> 6;
    int lane = threadIdx.x & 63;
    if (wid >= 41120) return;
    if (wid >= 40960) {
        // ao: 160 waves x 64 = 10240 elements
        int i = (wid - 40960)*64 + lane;
        int bt = i >> 8, c = i & 255;
        int lb = (bt & 3)*10 + (bt >> 2);
        float vg = 0.25f * (gates[(160 + lb)*256 + c] + gates[(200 + lb)*256 + c] +
                            gates[(240 + lb)*256 + c] + gates[(280 + lb)*256 + c]);
        out[42649600 + i] = audio[i] * (1.f + vg);
        return;
    }
    int t = wid / 10240, r = wid % 10240;
    int bt = r >> 8, c = r & 255;
    int lb = (bt & 3)*10 + (bt >> 2);
    const float* src; int hw; size_t obase; int gidx;
    if      (t == 0) { src = x4; hw = 49;   obase = 0;        gidx = (120 + lb)*256 + c; }
    else if (t == 1) { src = x3; hw = 196;  obase = 501760;   gidx = ( 80 + lb)*256 + c; }
    else if (t == 2) { src = x2; hw = 784;  obase = 2508800;  gidx = ( 40 + lb)*256 + c; }
    else             { src = x1; hw = 3136; obase = 10536960; gidx = r; }
    float scale = 1.f + gates[gidx];
    const float* row = src + (size_t)r * hw;
    float* orow = out + obase + (size_t)r * hw;
    if (hw == 49) {
        if (lane < 49) orow[lane] = row[lane] * scale;
    } else {
        int n4 = hw >> 2;
        for (int j = lane; j < n4; j += 64) {
            float4 v = *(const float4*)(row + j*4);
            v.x *= scale; v.y *= scale; v.z *= scale; v.w *= scale;
            *(float4*)(orow + j*4) = v;
        }
    }
}

extern "C" void kernel_launch(void* const* d_in, const int* in_sizes, int n_in,
                              void* d_out, int out_size, void* d_ws, size_t ws_size,
                              hipStream_t stream)
{
    const float* x1     = (const float*)d_in[0];
    const float* x2     = (const float*)d_in[1];
    const float* x3     = (const float*)d_in[2];
    const float* x4     = (const float*)d_in[3];
    const float* audio  = (const float*)d_in[4];
    const float* vis_w  = (const float*)d_in[5];
    const float* vis_b  = (const float*)d_in[6];
    const float* ln_g   = (const float*)d_in[7];
    const float* ln_b   = (const float*)d_in[8];
    const float* in_w   = (const float*)d_in[9];
    const float* conv_w = (const float*)d_in[10];
    const float* conv_b = (const float*)d_in[11];
    const float* xp_w   = (const float*)d_in[12];
    const float* dt_w   = (const float*)d_in[13];
    const float* dt_b   = (const float*)d_in[14];
    const float* A_log  = (const float*)d_in[15];
    const float* Dp     = (const float*)d_in[16];
    const float* out_w  = (const float*)d_in[17];
    const float* gate_w = (const float*)d_in[18];
    const float* gate_b = (const float*)d_in[19];

    float* ws  = (float*)d_ws;
    float* out = (float*)d_out;

    pool_kernel<<<dim3(10240), dim3(256), 0, stream>>>(x1, x2, x3, x4, ws + WS_POOLED);

    {
        const float* a0 = audio;  const float* a1 = vis_w;  const float* a2 = vis_b;
        const float* a3 = ln_g;   const float* a4 = ln_b;   const float* a5 = in_w;
        const float* a6 = conv_w; const float* a7 = conv_b; const float* a8 = xp_w;
        const float* a9 = dt_w;   const float* a10 = dt_b;  const float* a11 = A_log;
        const float* a12 = Dp;    const float* a13 = out_w; const float* a14 = gate_w;
        const float* a15 = gate_b; float* a16 = ws;
        void* args[17] = { &a0,&a1,&a2,&a3,&a4,&a5,&a6,&a7,&a8,&a9,&a10,&a11,&a12,
                           &a13,&a14,&a15,&a16 };
        hipLaunchCooperativeKernel((const void*)enc_coop, dim3(128), dim3(512),
                                   args, 0, stream);
    }

    scale_ao_kernel<<<dim3(10280), dim3(256), 0, stream>>>(x1, x2, x3, x4, audio,
                                                           ws + WS_GATES, out);
}

// Round 6
// 292.594 us; speedup vs baseline: 2.9466x; 2.9466x over previous
//
#include <hip/hip_runtime.h>

#define DM 256
#define DI 512
#define NL 10

// ws offsets (floats)
#define WS_POOLED 0
#define WS_GATES  40960
#define WS_SX     122880
#define WS_SH     204800
#define WS_XC     286720
#define WS_SZ     450560
#define WS_Y2     614400

__device__ __forceinline__ float dot4(float4 a, float4 b) {
    return a.x*b.x + a.y*b.y + a.z*b.z + a.w*b.w;
}
__device__ __forceinline__ float silu(float x) {
    return x / (1.f + __expf(-x));
}

// ---------------- Kernel 1: spatial mean pool of x1..x4 -> pooled (4,40,256)
__global__ void pool_kernel(const float* __restrict__ x1, const float* __restrict__ x2,
                            const float* __restrict__ x3, const float* __restrict__ x4,
                            float* __restrict__ pooled)
{
    int wid  = (blockIdx.x * blockDim.x + threadIdx.x) >> 6;
    int lane = threadIdx.x & 63;
    if (wid >= 40960) return;
    int img = wid / 10240;
    int r   = wid % 10240;
    const float* src; int hw;
    if      (img == 0) { src = x1; hw = 3136; }
    else if (img == 1) { src = x2; hw = 784; }
    else if (img == 2) { src = x3; hw = 196; }
    else               { src = x4; hw = 49; }
    const float* row = src + (size_t)r * hw;
    float s = 0.f;
    if (hw == 49) {
        if (lane < 49) s = row[lane];
    } else {
        int n4 = hw >> 2;
        for (int j = lane; j < n4; j += 64) {
            float4 v = *(const float4*)(row + j*4);
            s += v.x + v.y + v.z + v.w;
        }
    }
    #pragma unroll
    for (int off = 32; off; off >>= 1) s += __shfl_down(s, off);
    if (lane == 0) pooled[img*10240 + r] = s / (float)hw;
}

// ---------------- Kernel 2: build sx. blocks 0..255: vis GEMM (img,b,tile16).
// blocks 256..271: audio copy for e=0..3 ONLY.
__global__ __launch_bounds__(256)
void build_kernel(const float* __restrict__ audio, const float* __restrict__ vis_w,
                  const float* __restrict__ vis_b, float* __restrict__ ws)
{
    const int tid = threadIdx.x, bi = blockIdx.x;
    float* sxB = ws + WS_SX;
    if (bi >= 256) {
        const int idx = bi - 256, e = idx >> 2, b = idx & 3;   // e in 0..3 (audio)
        float* sx = sxB + (e*4+b)*2560;
        for (int i = tid; i < 2560; i += 256) sx[i] = audio[b*2560 + i];
        return;
    }
    __shared__ float act[NL*DM];
    const int img = bi >> 6, b = (bi >> 4) & 3, tile = bi & 15;
    const float* pooled = ws + WS_POOLED + img*10240 + b*2560;
    for (int i = tid; i < 2560; i += 256) act[i] = pooled[i];
    __syncthreads();
    const int wave = tid >> 6, lane = tid & 63;
    const int c4 = lane >> 4, k16 = lane & 15;
    const int col = tile*16 + wave*4 + c4;
    const float* wp = vis_w + img*65536 + col*256 + k16*4;
    float acc[NL];
    #pragma unroll
    for (int l = 0; l < NL; l++) acc[l] = 0.f;
    #pragma unroll
    for (int ko = 0; ko < 4; ko++) {
        float4 wv = *(const float4*)(wp + ko*64);
        #pragma unroll
        for (int l = 0; l < NL; l++)
            acc[l] += dot4(wv, *(const float4*)(&act[l*256 + ko*64 + k16*4]));
    }
    #pragma unroll
    for (int l = 0; l < NL; l++) {
        acc[l] += __shfl_xor(acc[l], 1);
        acc[l] += __shfl_xor(acc[l], 2);
        acc[l] += __shfl_xor(acc[l], 4);
        acc[l] += __shfl_xor(acc[l], 8);
    }
    if (k16 == 0) {
        float bias = vis_b[img*256 + col];
        float* sx = sxB + ((img+4)*4+b)*2560;
        #pragma unroll
        for (int l = 0; l < NL; l++) sx[l*256 + col] = bias + acc[l];
    }
}

// ---------------- Kernel 3: LN + xz GEMM + conv/silu (xi) or silu (z).
// grid = 8e*4b*64tile = 2048 blocks, 256 thr. tile = 16 cols of 1024.
__global__ __launch_bounds__(256)
void lnxz_kernel(const float* __restrict__ ln_g, const float* __restrict__ ln_b,
                 const float* __restrict__ in_w, const float* __restrict__ conv_w,
                 const float* __restrict__ conv_b, float* __restrict__ ws, int layer)
{
    __shared__ float act[NL*DM];     // LN output for this (e,b)
    const int tid = threadIdx.x, bi = blockIdx.x;
    const int e = bi >> 8, b = (bi >> 6) & 3, tile = bi & 63;
    const int el = e*3 + layer;
    const int wave = tid >> 6, lane = tid & 63;
    const float* sx = ws + WS_SX + (e*4+b)*2560;
    float* shg = ws + WS_SH + (e*4+b)*2560;

    for (int l = wave; l < NL; l += 4) {
        float4 v = *(const float4*)(sx + l*256 + lane*4);
        float s = v.x+v.y+v.z+v.w, ss = dot4(v, v);
        #pragma unroll
        for (int off = 32; off; off >>= 1) { s += __shfl_xor(s, off); ss += __shfl_xor(ss, off); }
        float m = s * (1.f/256.f);
        float rs = rsqrtf(ss*(1.f/256.f) - m*m + 1e-5f);
        float4 gv = *(const float4*)(ln_g + el*256 + lane*4);
        float4 bv = *(const float4*)(ln_b + el*256 + lane*4);
        float4 hv;
        hv.x = (v.x-m)*rs*gv.x + bv.x;
        hv.y = (v.y-m)*rs*gv.y + bv.y;
        hv.z = (v.z-m)*rs*gv.z + bv.z;
        hv.w = (v.w-m)*rs*gv.w + bv.w;
        *(float4*)(&act[l*256 + lane*4]) = hv;
        if (tile == 0) *(float4*)(shg + l*256 + lane*4) = hv;
    }
    __syncthreads();

    const int c4 = lane >> 4, k16 = lane & 15;
    const int col = tile*16 + wave*4 + c4;               // 0..1023
    const float* wp = in_w + (size_t)el*262144 + (size_t)col*256 + k16*4;
    float acc[NL];
    #pragma unroll
    for (int l = 0; l < NL; l++) acc[l] = 0.f;
    #pragma unroll
    for (int ko = 0; ko < 4; ko++) {
        float4 wv = *(const float4*)(wp + ko*64);
        #pragma unroll
        for (int l = 0; l < NL; l++)
            acc[l] += dot4(wv, *(const float4*)(&act[l*256 + ko*64 + k16*4]));
    }
    #pragma unroll
    for (int l = 0; l < NL; l++) {
        acc[l] += __shfl_xor(acc[l], 1);
        acc[l] += __shfl_xor(acc[l], 2);
        acc[l] += __shfl_xor(acc[l], 4);
        acc[l] += __shfl_xor(acc[l], 8);
    }
    if (k16 == 0) {
        if (col < 512) {
            float4 cw = *(const float4*)(conv_w + el*2048 + col*4);
            float cb = conv_b[el*512 + col];
            float* xc = ws + WS_XC + (e*4+b)*5120;
            float x0 = 0.f, x1 = 0.f, x2 = 0.f;
            #pragma unroll
            for (int l = 0; l < NL; l++) {
                float x3 = acc[l];
                float a = cb + x3*cw.w + x2*cw.z + x1*cw.y + x0*cw.x;
                xc[l*512 + col] = silu(a);
                x0 = x1; x1 = x2; x2 = x3;
            }
        } else {
            float* sz = ws + WS_SZ + (e*4+b)*5120;
            const int d = col - 512;
            #pragma unroll
            for (int l = 0; l < NL; l++) sz[l*512 + d] = silu(acc[l]);
        }
    }
}

// ---------------- Kernel 4: dbl GEMM + softplus + scan + z-gate -> y2.
// grid = 32 (e,b), 512 thr.
__global__ __launch_bounds__(512)
void dblscan_kernel(const float* __restrict__ xp_w, const float* __restrict__ dt_w,
                    const float* __restrict__ dt_b, const float* __restrict__ A_log,
                    const float* __restrict__ Dp,   float* __restrict__ ws, int layer)
{
    __shared__ float xc_l[NL*DI];
    __shared__ float dbl_l[NL*48];
    const int tid = threadIdx.x, bi = blockIdx.x;
    const int e = bi >> 2;
    const int el = e*3 + layer;
    const float* xc = ws + WS_XC + bi*5120;
    const float* sz = ws + WS_SZ + bi*5120;
    float* y2 = ws + WS_Y2 + bi*5120;

    for (int i = tid; i < 5120; i += 512) xc_l[i] = xc[i];
    __syncthreads();

    // dbl: 8 waves x 60 dots (r=t%48, l=t/48), K=512 split across 64 lanes
    {
        const int wave = tid >> 6, lane = tid & 63;
        for (int i = 0; i < 60; i++) {
            int t = wave*60 + i;
            int r = t % 48, l = t / 48;
            const float* w = xp_w + el*24576 + r*512;
            float p = dot4(*(const float4*)(w + lane*4),
                           *(const float4*)(&xc_l[l*512 + lane*4]))
                    + dot4(*(const float4*)(w + 256 + lane*4),
                           *(const float4*)(&xc_l[l*512 + 256 + lane*4]));
            #pragma unroll
            for (int off = 32; off; off >>= 1) p += __shfl_xor(p, off);
            if (lane == 0) dbl_l[l*48 + r] = p;
        }
    }
    __syncthreads();

    // scan: thread d
    {
        const int d = tid;
        const float* dwp = dt_w + el*8192 + d*16;
        float4 dw0 = *(const float4*)(dwp);
        float4 dw1 = *(const float4*)(dwp + 4);
        float4 dw2 = *(const float4*)(dwp + 8);
        float4 dw3 = *(const float4*)(dwp + 12);
        float dbv = dt_b[el*512 + d];
        float Dpv = Dp[el*512 + d];
        float Av[16];
        #pragma unroll
        for (int n = 0; n < 16; n++) Av[n] = -__expf(A_log[el*8192 + d*16 + n]);
        float h[16];
        #pragma unroll
        for (int n = 0; n < 16; n++) h[n] = 0.f;
        #pragma unroll
        for (int l = 0; l < NL; l++) {
            float4 t0 = *(const float4*)(&dbl_l[l*48]);
            float4 t1 = *(const float4*)(&dbl_l[l*48 + 4]);
            float4 t2 = *(const float4*)(&dbl_l[l*48 + 8]);
            float4 t3 = *(const float4*)(&dbl_l[l*48 + 12]);
            float a = dbv + dot4(t0,dw0) + dot4(t1,dw1) + dot4(t2,dw2) + dot4(t3,dw3);
            float dl = fmaxf(a, 0.f) + log1pf(__expf(-fabsf(a)));
            float xcv = xc_l[l*512 + d];
            float du = dl * xcv;
            float y = 0.f;
            #pragma unroll
            for (int n = 0; n < 16; n++) {
                float Bn = dbl_l[l*48 + 16 + n];
                float Cn = dbl_l[l*48 + 32 + n];
                h[n] = __expf(dl*Av[n])*h[n] + du*Bn;
                y += h[n]*Cn;
            }
            y2[l*512 + d] = (y + xcv*Dpv) * sz[l*512 + d];
        }
    }
}

// ---------------- Kernel 5: out GEMM + residual (sx = sh + y2 @ out_w.T).
// grid = 8e*4b*16tile = 512 blocks, 256 thr. K=512.
__global__ __launch_bounds__(256)
void out_kernel(const float* __restrict__ out_w, float* __restrict__ ws, int layer)
{
    __shared__ float act[NL*DI];     // y2 rows (20 KB)
    const int tid = threadIdx.x, bi = blockIdx.x;
    const int e = bi >> 6, b = (bi >> 4) & 3, tile = bi & 15;
    const int el = e*3 + layer;
    const float* y2 = ws + WS_Y2 + (e*4+b)*5120;
    for (int i = tid; i < 5120; i += 256) act[i] = y2[i];
    __syncthreads();

    const int wave = tid >> 6, lane = tid & 63;
    const int c4 = lane >> 4, k16 = lane & 15;
    const int col = tile*16 + wave*4 + c4;                // 0..255
    const float* wp = out_w + (size_t)el*131072 + (size_t)col*512 + k16*4;
    float acc[NL];
    #pragma unroll
    for (int l = 0; l < NL; l++) acc[l] = 0.f;
    #pragma unroll
    for (int ko = 0; ko < 8; ko++) {
        float4 wv = *(const float4*)(wp + ko*64);
        #pragma unroll
        for (int l = 0; l < NL; l++)
            acc[l] += dot4(wv, *(const float4*)(&act[l*512 + ko*64 + k16*4]));
    }
    #pragma unroll
    for (int l = 0; l < NL; l++) {
        acc[l] += __shfl_xor(acc[l], 1);
        acc[l] += __shfl_xor(acc[l], 2);
        acc[l] += __shfl_xor(acc[l], 4);
        acc[l] += __shfl_xor(acc[l], 8);
    }
    if (k16 == 0) {
        const float* sh = ws + WS_SH + (e*4+b)*2560;
        float* sx = ws + WS_SX + (e*4+b)*2560;
        #pragma unroll
        for (int l = 0; l < NL; l++) sx[l*256 + col] = sh[l*256 + col] + acc[l];
    }
}

// ---------------- Kernel 6: gate GEMM + silu. grid = 512 blocks (e,b,tile16), 256 thr.
__global__ __launch_bounds__(256)
void gate_kernel(const float* __restrict__ gate_w, const float* __restrict__ gate_b,
                 float* __restrict__ ws)
{
    __shared__ float act[NL*DM];
    const int tid = threadIdx.x, bi = blockIdx.x;
    const int e = bi >> 6, b = (bi >> 4) & 3, tile = bi & 15;
    const float* sx = ws + WS_SX + (e*4+b)*2560;
    for (int i = tid; i < 2560; i += 256) act[i] = sx[i];
    __syncthreads();

    const int wave = tid >> 6, lane = tid & 63;
    const int c4 = lane >> 4, k16 = lane & 15;
    const int col = tile*16 + wave*4 + c4;
    const float* wp = gate_w + e*65536 + col*256 + k16*4;
    float acc[NL];
    #pragma unroll
    for (int l = 0; l < NL; l++) acc[l] = 0.f;
    #pragma unroll
    for (int ko = 0; ko < 4; ko++) {
        float4 wv = *(const float4*)(wp + ko*64);
        #pragma unroll
        for (int l = 0; l < NL; l++)
            acc[l] += dot4(wv, *(const float4*)(&act[l*256 + ko*64 + k16*4]));
    }
    #pragma unroll
    for (int l = 0; l < NL; l++) {
        acc[l] += __shfl_xor(acc[l], 1);
        acc[l] += __shfl_xor(acc[l], 2);
        acc[l] += __shfl_xor(acc[l], 4);
        acc[l] += __shfl_xor(acc[l], 8);
    }
    if (k16 == 0) {
        float gb = gate_b[e*256 + col];
        float* gates = ws + WS_GATES;
        #pragma unroll
        for (int l = 0; l < NL; l++)
            gates[(e*40 + b*10 + l)*256 + col] = silu(gb + acc[l]);
    }
}

// ---------------- Kernel 7: x_out = x*(1+gate), plus ao tail blocks
__global__ void scale_ao_kernel(const float* __restrict__ x1, const float* __restrict__ x2,
                                const float* __restrict__ x3, const float* __restrict__ x4,
                                const float* __restrict__ audio,
                                const float* __restrict__ gates, float* __restrict__ out)
{
    int wid  = (blockIdx.x * blockDim.x + threadIdx.x) >> 6;
    int lane = threadIdx.x & 63;
    if (wid >= 41120) return;
    if (wid >= 40960) {
        int i = (wid - 40960)*64 + lane;
        int bt = i >> 8, c = i & 255;
        int lb = (bt & 3)*10 + (bt >> 2);
        float vg = 0.25f * (gates[(160 + lb)*256 + c] + gates[(200 + lb)*256 + c] +
                            gates[(240 + lb)*256 + c] + gates[(280 + lb)*256 + c]);
        out[42649600 + i] = audio[i] * (1.f + vg);
        return;
    }
    int t = wid / 10240, r = wid % 10240;
    int bt = r >> 8, c = r & 255;
    int lb = (bt & 3)*10 + (bt >> 2);
    const float* src; int hw; size_t obase; int gidx;
    if      (t == 0) { src = x4; hw = 49;   obase = 0;        gidx = (120 + lb)*256 + c; }
    else if (t == 1) { src = x3; hw = 196;  obase = 501760;   gidx = ( 80 + lb)*256 + c; }
    else if (t == 2) { src = x2; hw = 784;  obase = 2508800;  gidx = ( 40 + lb)*256 + c; }
    else             { src = x1; hw = 3136; obase = 10536960; gidx = r; }
    float scale = 1.f + gates[gidx];
    const float* row = src + (size_t)r * hw;
    float* orow = out + obase + (size_t)r * hw;
    if (hw == 49) {
        if (lane < 49) orow[lane] = row[lane] * scale;
    } else {
        int n4 = hw >> 2;
        for (int j = lane; j < n4; j += 64) {
            float4 v = *(const float4*)(row + j*4);
            v.x *= scale; v.y *= scale; v.z *= scale; v.w *= scale;
            *(float4*)(orow + j*4) = v;
        }
    }
}

extern "C" void kernel_launch(void* const* d_in, const int* in_sizes, int n_in,
                              void* d_out, int out_size, void* d_ws, size_t ws_size,
                              hipStream_t stream)
{
    const float* x1     = (const float*)d_in[0];
    const float* x2     = (const float*)d_in[1];
    const float* x3     = (const float*)d_in[2];
    const float* x4     = (const float*)d_in[3];
    const float* audio  = (const float*)d_in[4];
    const float* vis_w  = (const float*)d_in[5];
    const float* vis_b  = (const float*)d_in[6];
    const float* ln_g   = (const float*)d_in[7];
    const float* ln_b   = (const float*)d_in[8];
    const float* in_w   = (const float*)d_in[9];
    const float* conv_w = (const float*)d_in[10];
    const float* conv_b = (const float*)d_in[11];
    const float* xp_w   = (const float*)d_in[12];
    const float* dt_w   = (const float*)d_in[13];
    const float* dt_b   = (const float*)d_in[14];
    const float* A_log  = (const float*)d_in[15];
    const float* Dp     = (const float*)d_in[16];
    const float* out_w  = (const float*)d_in[17];
    const float* gate_w = (const float*)d_in[18];
    const float* gate_b = (const float*)d_in[19];

    float* ws  = (float*)d_ws;
    float* out = (float*)d_out;

    pool_kernel<<<dim3(10240), dim3(256), 0, stream>>>(x1, x2, x3, x4, ws + WS_POOLED);
    build_kernel<<<dim3(272), dim3(256), 0, stream>>>(audio, vis_w, vis_b, ws);
    for (int layer = 0; layer < 3; layer++) {
        lnxz_kernel<<<dim3(2048), dim3(256), 0, stream>>>(ln_g, ln_b, in_w, conv_w,
                                                          conv_b, ws, layer);
        dblscan_kernel<<<dim3(32), dim3(512), 0, stream>>>(xp_w, dt_w, dt_b, A_log,
                                                           Dp, ws, layer);
        out_kernel<<<dim3(512), dim3(256), 0, stream>>>(out_w, ws, layer);
    }
    gate_kernel<<<dim3(512), dim3(256), 0, stream>>>(gate_w, gate_b, ws);
    scale_ao_kernel<<<dim3(10280), dim3(256), 0, stream>>>(x1, x2, x3, x4, audio,
                                                           ws + WS_GATES, out);
}